// Round 17
// baseline (149.605 us; speedup 1.0000x reference)
//
#include <hip/hip_runtime.h>

typedef unsigned short u16;
typedef __attribute__((ext_vector_type(4))) float f32x4;
typedef __attribute__((ext_vector_type(8))) __bf16 bf16x8;
typedef __attribute__((ext_vector_type(8))) unsigned short us8;

#define NN (2048ull*2048ull)

// Tile-linear layout for big T-matrices: 256m x 16n tiles, m-major inside:
// addr(m,n) = ((n>>4)*8 + (m>>8))*4096 + (m&255)*16 + (n&15)

__device__ __forceinline__ u16 f2b(float x){
  union { float f; unsigned u; } v; v.f = x;
  unsigned r = v.u + 0x7FFFu + ((v.u >> 16) & 1u);
  return (u16)(r >> 16);
}
__device__ __forceinline__ float b2f(u16 x){
  union { unsigned u; float f; } v; v.u = ((unsigned)x) << 16; return v.f;
}

// ---- fast zero of the atomic-target region ----
__global__ __launch_bounds__(256)
void k_zero(float4* __restrict__ p, int n4){
  const float4 z = {0.f,0.f,0.f,0.f};
  for (int i = blockIdx.x*256 + threadIdx.x; i < n4; i += gridDim.x*256)
    p[i] = z;
}

// ---- fused 3-way mix: A -> A1T, A2T, BT (tile-linear) + colsums sA1, deg2.
//      v13: 256m x 16n tile; A staged via global_load_lds (1KB/wave contiguous);
//      thread t owns column m=m0+t (16 n values, 6 outputs = 96 f32 acc). ------------
__global__ __launch_bounds__(256)
void k_mix(const float* __restrict__ A,
           const float* __restrict__ w1, const float* __restrict__ w2,
           const float* __restrict__ wl,
           u16* __restrict__ A1T, u16* __restrict__ A2T, u16* __restrict__ BT,
           float* __restrict__ sA1, float* __restrict__ deg2){
  __shared__ float stg[16*256];   // 16 KB: stg[n_local*256 + m_local]
  const int t = threadIdx.x;
  const int mt = blockIdx.x;      // 0..7   (256-m tile)
  const int nt = blockIdx.y;      // 0..127 (16-n tile)
  const int m0 = mt*256, n0 = nt*16;

  float f[3][2][5];
  #pragma unroll
  for (int s=0;s<3;s++){
    const float* w = (s==0) ? w1 : (s==1) ? w2 : wl;
    #pragma unroll
    for (int c=0;c<2;c++){
      float m = -1e30f;
      #pragma unroll
      for (int e=0;e<5;e++) m = fmaxf(m, w[e*2+c]);
      float sum = 0.f;
      #pragma unroll
      for (int e=0;e<5;e++){ f[s][c][e] = __expf(w[e*2+c]-m); sum += f[s][c][e]; }
      float inv = 1.f/sum;
      #pragma unroll
      for (int e=0;e<5;e++) f[s][c][e] *= inv;
    }
  }

  float acc[6][16];
  #pragma unroll
  for (int sc=0;sc<6;sc++)
    #pragma unroll
    for (int n=0;n<16;n++) acc[sc][n] = 0.f;

  #pragma unroll
  for (int e=0;e<5;e++){
    // stage 16KB tile of A_e: each wave-issue = 1KB contiguous on one row
    #pragma unroll
    for (int it=0; it<4; ++it)
      __builtin_amdgcn_global_load_lds(
        (const __attribute__((address_space(1))) void*)
          (A + (size_t)e*NN + (size_t)(n0 + it*4 + (t>>6))*2048 + m0 + (t&63)*4),
        (__attribute__((address_space(3))) void*)(&stg[it*1024 + t*4]), 16, 0, 0);
    __syncthreads();
    #pragma unroll
    for (int n=0;n<16;n++){
      float a = stg[n*256 + t];
      #pragma unroll
      for (int s=0;s<3;s++)
        #pragma unroll
        for (int c=0;c<2;c++)
          acc[s*2+c][n] += a * f[s][c][e];
    }
    __syncthreads();
  }

  // colsum atomics (pre-rounding f32 sums): sA1 from A1, deg2 from B
  #pragma unroll
  for (int c=0;c<2;c++){
    float p1 = 0.f, pB = 0.f;
    #pragma unroll
    for (int n=0;n<16;n++){ p1 += acc[0+c][n]; pB += acc[4+c][n]; }
    atomicAdd(&sA1[c*2048 + m0 + t], p1);
    atomicAdd(&deg2[c*2048 + m0 + t], pB);
  }
  // stores: 8KB contiguous blob per (s,c)
  const size_t tb = (size_t)(nt*8 + mt)*4096 + (size_t)t*16;
  #pragma unroll
  for (int sc=0; sc<6; ++sc){
    u16* __restrict__ dst = (sc<2) ? A1T : (sc<4) ? A2T : BT;
    const int c = sc & 1;
    us8 v0, v1;
    #pragma unroll
    for (int q=0;q<8;q++){ v0[q] = f2b(acc[sc][q]); v1[q] = f2b(acc[sc][8+q]); }
    *(us8*)&dst[(size_t)c*NN + tb]     = v0;
    *(us8*)&dst[(size_t)c*NN + tb + 8] = v1;
  }
}

// ---- deg1[c][m] += sum_n A2T[m][n]*sA1[c][n]  (dense 8KB-tile reads) ----------------
__global__ __launch_bounds__(256)
void k_rdot(const u16* __restrict__ A2T, const float* __restrict__ sA1,
            float* __restrict__ deg1){
  const int mt = blockIdx.x, ng = blockIdx.y, c = blockIdx.z;
  const int t = threadIdx.x;
  const u16* __restrict__ Mc = A2T + (size_t)c*NN;
  const float* __restrict__ sv = sA1 + c*2048;
  float s = 0.f;
  #pragma unroll 2
  for (int q=0; q<16; ++q){
    const int ntile = ng*16 + q;
    const u16* base = Mc + (size_t)(ntile*8 + mt)*4096 + (size_t)t*16;
    us8 v0 = *(const us8*)base;
    us8 v1 = *(const us8*)(base + 8);
    const float4 f0 = *(const float4*)&sv[ntile*16 + 0];
    const float4 f1 = *(const float4*)&sv[ntile*16 + 4];
    const float4 f2 = *(const float4*)&sv[ntile*16 + 8];
    const float4 f3 = *(const float4*)&sv[ntile*16 + 12];
    s += b2f(v0[0])*f0.x + b2f(v0[1])*f0.y + b2f(v0[2])*f0.z + b2f(v0[3])*f0.w
       + b2f(v0[4])*f1.x + b2f(v0[5])*f1.y + b2f(v0[6])*f1.z + b2f(v0[7])*f1.w
       + b2f(v1[0])*f2.x + b2f(v1[1])*f2.y + b2f(v1[2])*f2.z + b2f(v1[3])*f2.w
       + b2f(v1[4])*f3.x + b2f(v1[5])*f3.y + b2f(v1[6])*f3.z + b2f(v1[7])*f3.w;
  }
  atomicAdd(&deg1[c*2048 + mt*256 + t], s);
}

// ---- weighted column-sum over m (tile-linear): outv[c][n] += sum_m w[m]*MT[m][n] ----
// MODE 0: w=inv(va[m]) ; MODE 1: w=inv(va[m])*vb[m] ; MODE 2: w=va[m]
template<int MODE>
__global__ __launch_bounds__(256)
void k_wsum(const u16* __restrict__ MT, const float* __restrict__ va,
            const float* __restrict__ vb, float* __restrict__ outv){
  __shared__ float w[512];
  __shared__ float red[16][17];
  const int t = threadIdx.x;
  const int nt = blockIdx.x, mgrp = blockIdx.y, c = blockIdx.z;
  #pragma unroll
  for (int i=t; i<512; i+=256){
    const int m = c*2048 + mgrp*512 + i;
    float x;
    if (MODE == 0){ float d = va[m]; x = d > 0.f ? 1.f/d : 0.f; }
    else if (MODE == 1){ float d = va[m]; x = (d > 0.f ? 1.f/d : 0.f) * vb[m]; }
    else { x = va[m]; }
    w[i] = x;
  }
  __syncthreads();
  const int n = t & 15, mg = t >> 4;
  float s = 0.f;
  #pragma unroll
  for (int mt2=0; mt2<2; ++mt2){
    const u16* __restrict__ base = MT + (size_t)c*NN
        + (size_t)(nt*8 + mgrp*2 + mt2)*4096 + n;
    #pragma unroll 4
    for (int mm=0; mm<16; ++mm){
      const int ml = mg*16 + mm;
      s += b2f(base[ml*16]) * w[mt2*256 + ml];
    }
  }
  red[mg][n] = s;
  __syncthreads();
  if (t < 16){
    float sum = 0.f;
    #pragma unroll
    for (int g=0; g<16; ++g) sum += red[g][t];
    atomicAdd(&outv[c*2048 + nt*16 + t], sum);
  }
}

// ---- fused hw = h@gcn_w then PT[c][d][n] = bf16(rsqrt(max(rowsum,1))*hw[n][d]) ------
// PT stays ROW-major [c][128][2048]
__global__ __launch_bounds__(256)
void k_hwpt(const float* __restrict__ h, const float* __restrict__ W,
            const float* __restrict__ rowsum, u16* __restrict__ PT){
  __shared__ float lh[8][256];
  int t = threadIdx.x;
  int n0 = blockIdx.x * 8;
  for (int idx = t; idx < 8*256; idx += 256)
    lh[idx >> 8][idx & 255] = h[(size_t)(n0 + (idx>>8))*256 + (idx&255)];
  __syncthreads();
  int d = t & 127, half = t >> 7;
  float acc[4];
  #pragma unroll
  for (int nn=0;nn<4;nn++) acc[nn] = 0.f;
  for (int k=0;k<256;k++){
    float wv = W[(size_t)k*128 + d];
    #pragma unroll
    for (int nn=0;nn<4;nn++) acc[nn] += lh[half*4+nn][k]*wv;
  }
  #pragma unroll
  for (int c=0;c<2;c++){
    ushort4 o;
    #pragma unroll
    for (int nn=0;nn<4;nn++){
      int n = n0 + half*4 + nn;
      float dv = rsqrtf(fmaxf(rowsum[c*2048 + n], 1.0f));
      ((u16*)&o)[nn] = f2b(dv * acc[nn]);
    }
    *(ushort4*)&PT[((size_t)c*128 + d)*2048 + n0 + half*4] = o;
  }
}

// ------- thin bt-GEMM split-K=8, atomic f32 C: Agg += A(tile-linear) @ Bt(row-major)^T
__global__ __launch_bounds__(256, 2)
void k_gemm3(const u16* __restrict__ A, const u16* __restrict__ Bt, float* __restrict__ Agg){
  __shared__ u16 lA[128*64];
  __shared__ u16 lB[128*64];
  const int tid = threadIdx.x;
  const int bm = blockIdx.x, bk = blockIdx.y, cc = blockIdx.z;
  const u16* __restrict__ Bb = Bt + (size_t)cc*(128*2048) + bk*256;
  float* __restrict__ Cb = Agg + (size_t)cc*2048*128 + (size_t)(bm*128)*128;
  const int wid = tid >> 6, lane = tid & 63;
  const int wr = wid >> 1, wc = wid & 1;
  const int fl = lane & 15, fk = (lane >> 4) << 3;
  const int srow = (wid << 3) + (lane >> 3);   // 0..31
  const int scol = (lane & 7) << 3;

  f32x4 acc[4][4];
  const f32x4 zero = {0.f,0.f,0.f,0.f};
  #pragma unroll
  for (int i=0;i<4;i++)
    #pragma unroll
    for (int jj=0;jj<4;jj++) acc[i][jj] = zero;

  for (int k0 = 0; k0 < 256; k0 += 64){
    #pragma unroll
    for (int it = 0; it < 4; ++it){
      // A operand (tile-linear): m = bm*128 + it*32 + srow ; n = bk*256 + k0 + scol
      const int m = bm*128 + it*32 + srow;
      const int n = bk*256 + k0 + scol;
      const u16* srcA = A + (size_t)cc*NN
          + (size_t)((n>>4)*8 + (m>>8))*4096 + (size_t)(m&255)*16 + (n&15);
      __builtin_amdgcn_global_load_lds(
        (const __attribute__((address_space(1))) void*)srcA,
        (__attribute__((address_space(3))) void*)(&lA[(it*32 + (wid<<3))*64]), 16, 0, 0);
      int r = it*32 + srow;
      __builtin_amdgcn_global_load_lds(
        (const __attribute__((address_space(1))) void*)(Bb + (size_t)r*2048 + k0 + scol),
        (__attribute__((address_space(3))) void*)(&lB[(it*32 + (wid<<3))*64]), 16, 0, 0);
    }
    __syncthreads();
    #pragma unroll
    for (int ks = 0; ks < 2; ++ks){
      bf16x8 af[4], bfr[4];
      #pragma unroll
      for (int mi=0;mi<4;mi++)
        af[mi] = *reinterpret_cast<const bf16x8*>(&lA[(wr*64 + mi*16 + fl)*64 + ks*32 + fk]);
      #pragma unroll
      for (int ni=0;ni<4;ni++)
        bfr[ni] = *reinterpret_cast<const bf16x8*>(&lB[(wc*64 + ni*16 + fl)*64 + ks*32 + fk]);
      #pragma unroll
      for (int mi=0;mi<4;mi++)
        #pragma unroll
        for (int ni=0;ni<4;ni++)
          acc[mi][ni] = __builtin_amdgcn_mfma_f32_16x16x32_bf16(af[mi], bfr[ni], acc[mi][ni], 0, 0, 0);
    }
    __syncthreads();
  }
  const int rbase = (lane >> 4) << 2;
  #pragma unroll
  for (int mi=0;mi<4;mi++)
    #pragma unroll
    for (int ni=0;ni<4;ni++)
      #pragma unroll
      for (int r=0;r<4;r++)
        atomicAdd(&Cb[(size_t)(wr*64 + mi*16 + rbase + r)*128 + wc*64 + ni*16 + fl],
                  acc[mi][ni][r]);
}

// ---- Agg f32 [c][2048][128] (+ optional dinv1 row scale) -> row-major bf16 QT -------
template<bool SCALE>
__global__ __launch_bounds__(256)
void k_qt(const float* __restrict__ Agg, const float* __restrict__ deg1,
          u16* __restrict__ QT){
  __shared__ u16 lq[128][36];
  const int t = threadIdx.x;
  const int m0 = blockIdx.x * 32, c = blockIdx.y;
  const int d4 = (t & 31) * 4, mr = t >> 5;
  #pragma unroll
  for (int p4=0; p4<4; ++p4){
    const int m = m0 + p4*8 + mr;
    float4 s = *(const float4*)&Agg[((size_t)c*2048 + m)*128 + d4];
    if (SCALE){
      float dg = deg1[c*2048 + m];
      float di = dg > 0.f ? 1.f/dg : 0.f;
      s.x *= di; s.y *= di; s.z *= di; s.w *= di;
    }
    const int ml = p4*8 + mr;
    lq[d4+0][ml] = f2b(s.x); lq[d4+1][ml] = f2b(s.y);
    lq[d4+2][ml] = f2b(s.z); lq[d4+3][ml] = f2b(s.w);
  }
  __syncthreads();
  const int d = t >> 1, half = t & 1;
  u16* __restrict__ dst = QT + ((size_t)c*128 + d)*2048 + m0 + half*16;
  #pragma unroll
  for (int q=0;q<4;q++){
    ushort4 o;
    o.x = lq[d][half*16 + q*4 + 0];
    o.y = lq[d][half*16 + q*4 + 1];
    o.z = lq[d][half*16 + q*4 + 2];
    o.w = lq[d][half*16 + q*4 + 3];
    *(ushort4*)&dst[q*4] = o;
  }
}

// -------- head: Xc = relu(dinv2[c,m]*agg3 + gb); out = relu(Xc@W1+b1)@W2+b2 ----------
__global__ __launch_bounds__(256)
void k_head(const float* __restrict__ agg3, const float* __restrict__ deg2,
            const float* __restrict__ gb,
            const float* __restrict__ W1, const float* __restrict__ b1,
            const float* __restrict__ W2, const float* __restrict__ b2,
            float* __restrict__ out){
  __shared__ float lx[8][256];
  __shared__ float lt[8][132];
  int t = threadIdx.x;
  int n0 = blockIdx.x * 8;
  for (int idx = t; idx < 512; idx += 256){
    int row = idx >> 6;
    int q = idx & 63;
    int c = q >> 5, d4 = (q & 31) * 4;
    float dg = deg2[c*2048 + n0 + row];
    float di = dg > 0.f ? 1.f/dg : 0.f;
    float4 s = *(const float4*)&agg3[((size_t)c*2048 + n0 + row)*128 + d4];
    const float4 bv = *(const float4*)&gb[d4];
    s.x = fmaxf(s.x*di + bv.x, 0.f); s.y = fmaxf(s.y*di + bv.y, 0.f);
    s.z = fmaxf(s.z*di + bv.z, 0.f); s.w = fmaxf(s.w*di + bv.w, 0.f);
    *(float4*)&lx[row][c*128 + d4] = s;
  }
  __syncthreads();
  int d = t & 127, half = t >> 7;
  float acc[4];
  #pragma unroll
  for (int nn=0;nn<4;nn++) acc[nn] = 0.f;
  for (int k=0;k<256;k++){
    float wv = W1[(size_t)k*128 + d];
    #pragma unroll
    for (int nn=0;nn<4;nn++) acc[nn] += lx[half*4+nn][k]*wv;
  }
  float bb = b1[d];
  #pragma unroll
  for (int nn=0;nn<4;nn++){
    float v = acc[nn] + bb;
    lt[half*4+nn][d] = v > 0.f ? v : 0.f;
  }
  __syncthreads();
  if (t < 128){
    int row = t >> 4, q = t & 15;
    float s = b2[q];
    for (int dd=0; dd<128; dd++) s += lt[row][dd] * W2[(size_t)dd*16 + q];
    out[(size_t)(n0+row)*16 + q] = s;
  }
}

extern "C" void kernel_launch(void* const* d_in, const int* in_sizes, int n_in,
                              void* d_out, int out_size, void* d_ws, size_t ws_size,
                              hipStream_t stream){
  const float* A   = (const float*)d_in[0];
  const float* h   = (const float*)d_in[1];
  const float* w1  = (const float*)d_in[2];
  const float* w2  = (const float*)d_in[3];
  const float* wl  = (const float*)d_in[4];
  const float* gw  = (const float*)d_in[5];
  const float* gb  = (const float*)d_in[6];
  const float* l1w = (const float*)d_in[7];
  const float* l1b = (const float*)d_in[8];
  const float* l2w = (const float*)d_in[9];
  const float* l2b = (const float*)d_in[10];
  float* out = (float*)d_out;
  char* ws = (char*)d_ws;

  const size_t SZ = 2*NN*2;     // 16.78 MB (one bf16 [2][...] tile-linear matrix)
  const size_t AGG = (size_t)2*2048*128*4;   // 2 MB
  u16*  A1T  = (u16*)(ws);
  u16*  A2T  = (u16*)(ws + 1*SZ);
  u16*  BT   = (u16*)(ws + 2*SZ);
  char* tail = ws + 3*SZ;
  u16*  PT     = (u16*)tail;                      // 1MB (row-major)
  u16*  Q1T    = (u16*)(tail + 1048576);          // 1MB (row-major)
  u16*  Q2T    = (u16*)(tail + 2*1048576);        // 1MB (row-major)
  float* sA1   = (float*)(tail + 3*1048576);      // zeroed region starts here
  float* deg1  = sA1 + 4096;
  float* deg2  = deg1 + 4096;
  float* v1    = deg2 + 4096;
  float* v3    = v1 + 4096;
  float* rowsum= v3 + 4096;
  float* agg1  = rowsum + 4096;                   // 3 x 2MB
  float* agg2  = agg1 + 2*2048*128;
  float* agg3  = agg2 + 2*2048*128;
  const size_t ZBYTES = 6*4096*4 + 3*AGG;

  const size_t TOTAL = 3*SZ + 3*1048576 + ZBYTES;
  if (ws_size < TOTAL){ hipMemsetAsync(d_out, 0, (size_t)out_size*4, stream); return; }

  k_zero<<<1024, 256, 0, stream>>>((float4*)sA1, (int)(ZBYTES/16));

  // A -> A1T, A2T, BT (tile-linear) + sA1 (colsum A1), deg2 (colsum B)
  k_mix<<<dim3(8,128), 256, 0, stream>>>(A, w1, w2, wl, A1T, A2T, BT, sA1, deg2);
  // deg1 = sA1 @ A2 (dense-tile weighted row-dots)
  k_rdot<<<dim3(8,8,2), 256, 0, stream>>>(A2T, sA1, deg1);
  // v1 = B@dinv2 ; v3 = A2@(dinv1*v1) ; rowsum = A1@v3
  k_wsum<0><<<dim3(128,4,2), 256, 0, stream>>>(BT, deg2, deg2, v1);
  k_wsum<1><<<dim3(128,4,2), 256, 0, stream>>>(A2T, deg1, v1, v3);
  k_wsum<2><<<dim3(128,4,2), 256, 0, stream>>>(A1T, v3, v3, rowsum);
  // features: PT = dout * (h@gcn_w)^T
  k_hwpt<<<256, 256, 0, stream>>>(h, gw, rowsum, PT);
  // agg chain: Q1 = A1^T@P ; Q2 = dinv1*(A2^T@Q1) ; agg3 = B^T@Q2 ; (dinv2 in head)
  k_gemm3<<<dim3(16,8,2), 256, 0, stream>>>(A1T, PT, agg1);
  k_qt<false><<<dim3(64,2), 256, 0, stream>>>(agg1, deg1, Q1T);
  k_gemm3<<<dim3(16,8,2), 256, 0, stream>>>(A2T, Q1T, agg2);
  k_qt<true><<<dim3(64,2), 256, 0, stream>>>(agg2, deg1, Q2T);
  k_gemm3<<<dim3(16,8,2), 256, 0, stream>>>(BT, Q2T, agg3);
  k_head<<<256, 256, 0, stream>>>(agg3, deg2, gb, l1w, l1b, l2w, l2b, out);
}